// Round 10
// baseline (312.051 us; speedup 1.0000x reference)
//
#include <hip/hip_runtime.h>
#include <cstdint>
#include <cstddef>

// Problem constants
constexpr int T_N = 8192;   // rows of x / out
constexpr int MM  = 4096;   // K (cols of x, cols of W)
constexpr int NN  = 4096;   // rows of W / cols of out
constexpr int S_L = 2048;
constexpr int S_R = 2048;
constexpr float EPS_ = 1e-6f;

typedef float  f32x4   __attribute__((ext_vector_type(4)));
typedef __bf16 bf16x8  __attribute__((ext_vector_type(8)));
typedef unsigned short ushort8 __attribute__((ext_vector_type(8)));

__device__ __forceinline__ unsigned short f2bf(float f) {
  unsigned int u = __float_as_uint(f);
  u += 0x7FFFu + ((u >> 16) & 1u);   // round-to-nearest-even
  return (unsigned short)(u >> 16);
}

// ---------------------------------------------------------------------------
// Kernel 1: identity column maps
// ---------------------------------------------------------------------------
__global__ void init_cols(float* colC, float* colS, int* colP) {
  int i = blockIdx.x * blockDim.x + threadIdx.x;
  if (i < MM) { colC[i] = 1.f; colS[i] = 0.f; colP[i] = i; }
}

// ---------------------------------------------------------------------------
// Kernel 2: column rotation maps from (pairs_R, theta_R).
// ---------------------------------------------------------------------------
__global__ void build_cols(const float* __restrict__ thR, const int* __restrict__ prR,
                           float* colC, float* colS, int* colP) {
  int s = blockIdx.x * blockDim.x + threadIdx.x;
  if (s < S_R) {
    int i = prR[2*s], j = prR[2*s+1];
    float c = cosf(thR[s]), sn = sinf(thR[s]);
    colC[i] = c; colS[i] = -sn; colP[i] = j;
    colC[j] = c; colS[j] =  sn; colP[j] = i;
  }
}

// ---------------------------------------------------------------------------
// Kernel 3 (fused): bid < S_L  -> W_eff pair build (rows i,j of pair s=bid)
//                   bid >= S_L -> x f32->bf16 conversion chunk
// ---------------------------------------------------------------------------
__global__ __launch_bounds__(256) void weff_conv(
    const float* __restrict__ W, const float* __restrict__ brn, const float* __restrict__ elm,
    const float* __restrict__ thL, const int* __restrict__ prL,
    const float* __restrict__ colC, const float* __restrict__ colS, const int* __restrict__ colP,
    unsigned short* __restrict__ Wb,
    const float* __restrict__ x, unsigned short* __restrict__ xb)
{
  __shared__ __align__(16) float rI[MM];
  __shared__ __align__(16) float rJ[MM];
  __shared__ float red[8];

  int bid = blockIdx.x;
  int tid = threadIdx.x;

  if (bid >= S_L) {
    const size_t total = (size_t)T_N * MM / 8;
    for (size_t i = (size_t)(bid - S_L) * 256 + tid; i < total; i += 2048ull * 256ull) {
      const float* s = x + i * 8;
      f32x4 v0 = *(const f32x4*)s;
      f32x4 v1 = *(const f32x4*)(s + 4);
      ushort8 p;
      p[0] = f2bf(v0.x); p[1] = f2bf(v0.y); p[2] = f2bf(v0.z); p[3] = f2bf(v0.w);
      p[4] = f2bf(v1.x); p[5] = f2bf(v1.y); p[6] = f2bf(v1.z); p[7] = f2bf(v1.w);
      *(ushort8*)(xb + i * 8) = p;
    }
    return;
  }

  int s = bid;
  int i = prL[2*s], j = prL[2*s+1];
  float cl = cosf(thL[s]), sl = sinf(thL[s]);
  const float* Wi = W + (size_t)i * MM;
  const float* Wj = W + (size_t)j * MM;

  for (int m = tid * 4; m < MM; m += 1024) {
    *(f32x4*)&rI[m] = *(const f32x4*)&Wi[m];
    *(f32x4*)&rJ[m] = *(const f32x4*)&Wj[m];
  }
  __syncthreads();

  float ssi = 0.f, ssj = 0.f;
  for (int m = tid; m < MM; m += 256) {
    int p = colP[m];
    float c = colC[m], sn = colS[m];
    float vi = c * rI[m] + sn * rI[p];
    float vj = c * rJ[m] + sn * rJ[p];
    float ei = cl * vi - sl * vj;
    float ej = sl * vi + cl * vj;
    ssi += ei * ei;
    ssj += ej * ej;
  }
  #pragma unroll
  for (int o = 32; o; o >>= 1) { ssi += __shfl_xor(ssi, o); ssj += __shfl_xor(ssj, o); }
  int lane = tid & 63, wid = tid >> 6;
  if (lane == 0) { red[wid] = ssi; red[4 + wid] = ssj; }
  __syncthreads();
  float ti = red[0] + red[1] + red[2] + red[3];
  float tj = red[4] + red[5] + red[6] + red[7];
  float sci = brn[i] * expf(elm[i]) / sqrtf(ti + EPS_);
  float scj = brn[j] * expf(elm[j]) / sqrtf(tj + EPS_);

  for (int m0 = tid * 8; m0 < MM; m0 += 2048) {
    ushort8 pi, pj;
    #pragma unroll
    for (int q = 0; q < 8; q++) {
      int m = m0 + q;
      int p = colP[m];
      float c = colC[m], sn = colS[m];
      float vi = c * rI[m] + sn * rI[p];
      float vj = c * rJ[m] + sn * rJ[p];
      pi[q] = f2bf((cl * vi - sl * vj) * sci);
      pj[q] = f2bf((sl * vi + cl * vj) * scj);
    }
    *(ushort8*)&Wb[(size_t)i * MM + m0] = pi;
    *(ushort8*)&Wb[(size_t)j * MM + m0] = pj;
  }
}

// ---------------------------------------------------------------------------
// global->LDS async staging helper (16B, linear LDS dest)
// ---------------------------------------------------------------------------
typedef const __attribute__((address_space(1))) unsigned int* as1_u32p;
typedef __attribute__((address_space(3))) unsigned int* as3_u32p;

__device__ __forceinline__ void gl_lds16(const void* g, void* l) {
  __builtin_amdgcn_global_load_lds((as1_u32p)g, (as3_u32p)l, 16, 0, 0);
}

// ---------------------------------------------------------------------------
// Kernel 5a: 256x256 GEMM — 4-phase reads-in-MFMA-shadow schedule.
//   BK=64, 8 waves (2Mx4N), per-wave 128x64, acc[8][4], 16x16x32 bf16 MFMA.
//   LDS 128 KiB dbuf.  ONE barrier per phase (4/tile); each phase:
//     lgkm(0) [ops issued last phase] -> issue next-phase ds_reads ->
//     setprio(1) 16 MFMA setprio(0) -> stage 1 half-tile -> BAR
//   Reads drain under the MFMA cluster; only barrier+stage issue exposed.
//   Slots: P1: B1(t+1)->buf^1;  P2: B0(t+2)->buf;  P3: A0(t+2)->buf +
//   GATE vmcnt(4);  P4: A1(t+2)->buf + RD a0,b0(t+1) from buf^1.
//   Ledger (FIFO, 2 loads/half-tile): at gate(P3(t)) queue =
//   [B0(t+1),A0(t+1),A1(t+1),B1(t+1),B0(t+2),A0(t+2)] (12) -> vmcnt(4)
//   retires 8 = all of t+1 before the P4 reads (RAW ✓).  WAR: every staged
//   region was lgkm(0)-waited per wave >= 1 barrier before its stage ✓.
//   (a0,b0) ping-pong across tiles via static register sets A/B.
//   Swizzle (r2-verified, 0 conflicts): stage src col-group ^= (row&7);
//   read byte addr: row*128 + ((kk*64+lg*16) ^ ((lr&7)<<4)).
// ---------------------------------------------------------------------------
constexpr int GBM = 256, GBN = 256, GBK = 64;
constexpr int NTK = MM / GBK;              // 64 K-tiles
constexpr int BUFB = GBM * GBK * 2;        // 32 KiB per operand per buffer

#define SB0() __builtin_amdgcn_sched_barrier(0)
#define BAR() __builtin_amdgcn_s_barrier()
#define LGKM0() do { asm volatile("s_waitcnt lgkmcnt(0)" ::: "memory"); \
                     SB0(); } while (0)

#define RD_A8(DST, AB, MIH)                                                   \
  _Pragma("unroll") for (int i_ = 0; i_ < 4; ++i_)                            \
  _Pragma("unroll") for (int k_ = 0; k_ < 2; ++k_)                            \
    DST[i_][k_] = *(const bf16x8*)((AB) + arow0 + ((MIH) * 4 + i_) * 2048     \
                                    + ((k_ * 64 + lg * 16) ^ sw));

#define RD_B4(DST, BB, NIH)                                                   \
  _Pragma("unroll") for (int n_ = 0; n_ < 2; ++n_)                            \
  _Pragma("unroll") for (int k_ = 0; k_ < 2; ++k_)                            \
    DST[n_][k_] = *(const bf16x8*)((BB) + brow0 + ((NIH) * 2 + n_) * 2048     \
                                    + ((k_ * 64 + lg * 16) ^ sw));

#define QMF(AF, BF, MI0, NI0)                                                 \
  __builtin_amdgcn_s_setprio(1);                                              \
  _Pragma("unroll") for (int k_ = 0; k_ < 2; ++k_)                            \
  _Pragma("unroll") for (int i_ = 0; i_ < 4; ++i_)                            \
  _Pragma("unroll") for (int n_ = 0; n_ < 2; ++n_)                            \
    acc[(MI0) + i_][(NI0) + n_] = __builtin_amdgcn_mfma_f32_16x16x32_bf16(    \
        AF[i_][k_], BF[n_][k_], acc[(MI0) + i_][(NI0) + n_], 0, 0, 0);        \
  __builtin_amdgcn_s_setprio(0);

#define STG_A(KOF, BUF, H)                                                    \
  _Pragma("unroll") for (int l_ = 2 * (H); l_ < 2 * (H) + 2; ++l_)            \
    gl_lds16(sA + (size_t)l_ * (64 * MM) + (KOF),                             \
             ldsA + (BUF) * BUFB + dstb + l_ * 8192);
#define STG_B(KOF, BUF, H)                                                    \
  _Pragma("unroll") for (int l_ = 2 * (H); l_ < 2 * (H) + 2; ++l_)            \
    gl_lds16(sB + (size_t)l_ * (64 * MM) + (KOF),                             \
             ldsB + (BUF) * BUFB + dstb + l_ * 8192);

#define GATE4x asm volatile("s_waitcnt vmcnt(4)" ::: "memory")
#define GATE0x asm volatile("s_waitcnt vmcnt(0)" ::: "memory")
#define GNONE  do { } while (0)

// Per-tile body.  a0C/b0C: this tile's Q1/Q4 operands (already read).
// a0N/b0N: filled in P4 with next tile's operands from buf^1.
#define TILEX(T, BB, a0C, b0C, a0N, b0N, DOB1, DOT2, GATE3, DORDN)            \
  {                                                                           \
    const char* Ab_  = ldsA + (BB) * BUFB;                                    \
    const char* Bb_  = ldsB + (BB) * BUFB;                                    \
    const char* AbN_ = ldsA + ((BB) ^ 1) * BUFB;                              \
    const char* BbN_ = ldsB + ((BB) ^ 1) * BUFB;                              \
    bf16x8 a1[4][2], b1[2][2];                                                \
    /* P1: wait a0,b0; read a1 under Q1; stage B1(t+1) */                     \
    LGKM0();                                                                  \
    RD_A8(a1, Ab_, 1);                                                        \
    SB0();                                                                    \
    QMF(a0C, b0C, 0, 0);                                                      \
    if (DOB1) { STG_B(((T) + 1) * GBK, (BB) ^ 1, 1); }                        \
    BAR();                                                                    \
    /* P2: wait a1; read b1 under Q2; stage B0(t+2) */                        \
    LGKM0();                                                                  \
    RD_B4(b1, Bb_, 1);                                                        \
    SB0();                                                                    \
    QMF(a1, b0C, 4, 0);                                                       \
    if (DOT2) { STG_B(((T) + 2) * GBK, (BB), 0); }                            \
    BAR();                                                                    \
    /* P3: wait b1; Q3; stage A0(t+2); counted gate */                        \
    LGKM0();                                                                  \
    QMF(a1, b1, 4, 2);                                                        \
    if (DOT2) { STG_A(((T) + 2) * GBK, (BB), 0); }                            \
    GATE3;                                                                    \
    BAR();                                                                    \
    /* P4: read a0,b0(t+1) under Q4 (held regs); stage A1(t+2) */             \
    if (DORDN) { RD_B4(b0N, BbN_, 0); RD_A8(a0N, AbN_, 0); SB0(); }           \
    QMF(a0C, b1, 0, 2);                                                       \
    if (DOT2) { STG_A(((T) + 2) * GBK, (BB), 1); }                            \
    BAR();                                                                    \
  }

__global__ __launch_bounds__(512, 2) void gemm8(
    const unsigned short* __restrict__ xb,
    const unsigned short* __restrict__ wb,
    const float* __restrict__ bias,
    float* __restrict__ C)
{
  __shared__ __align__(16) unsigned short As[2 * GBM * GBK];  // 64 KiB
  __shared__ __align__(16) unsigned short Bs[2 * GBN * GBK];  // 64 KiB
  char* ldsA = (char*)As;
  char* ldsB = (char*)Bs;

  // grid = 512 = 32 (tm) x 16 (tn); XCD swizzle, tn-fast within an XCD.
  int bid = blockIdx.x;
  int swz = (bid & 7) * 64 + (bid >> 3);
  int tn = swz & 15, tm = swz >> 4;
  const int trow0 = tm * GBM;
  const int tcol0 = tn * GBN;

  int tid  = threadIdx.x;
  int lane = tid & 63;
  int wid  = tid >> 6;
  int wr = wid >> 2, wc = wid & 3;   // wave coords: 2 x 4
  int lr = lane & 15;                // fragment row/col
  int lg = lane >> 4;                // k-group (8 bf16 = 16B)
  const int sw = (lr & 7) << 4;      // swizzle byte term
  const int arow0 = (wr * 128 + lr) * 128;  // A row base bytes
  const int brow0 = (wc * 64  + lr) * 128;  // B row base bytes

  // staging geometry: granule l covers rows r0 + 64*l; const col group
  const int r0   = tid >> 3;
  const int colg = (tid & 7) ^ (r0 & 7);
  const unsigned short* sA = xb + (size_t)(trow0 + r0) * MM + colg * 8;
  const unsigned short* sB = wb + (size_t)(tcol0 + r0) * MM + colg * 8;
  const int dstb = tid * 16;

  f32x4 acc[8][4];
  #pragma unroll
  for (int i = 0; i < 8; i++)
    #pragma unroll
    for (int j = 0; j < 4; j++) {
      f32x4 z = {0.f, 0.f, 0.f, 0.f};
      acc[i][j] = z;
    }

  // ---- prologue: t0 full -> buf0; t1 {B0,A0,A1} -> buf1 (FIFO order!);
  //      vmcnt(6) retires t0's 4 halves; then read a0,b0 of tile 0 ----
  STG_A(0, 0, 0); STG_A(0, 0, 1); STG_B(0, 0, 0); STG_B(0, 0, 1);
  STG_B(GBK, 1, 0); STG_A(GBK, 1, 0); STG_A(GBK, 1, 1);
  asm volatile("s_waitcnt vmcnt(6)" ::: "memory");
  __builtin_amdgcn_s_barrier();

  bf16x8 a0A[4][2], b0A[2][2], a0B[4][2], b0B[2][2];
  RD_B4(b0A, ldsB, 0);
  RD_A8(a0A, ldsA, 0);

  // ---- main loop: tiles 0..61 ----
  #pragma unroll 1
  for (int t = 0; t < NTK - 2; t += 2) {
    TILEX(t,     0, a0A, b0A, a0B, b0B, 1, 1, GATE4x, 1);
    TILEX(t + 1, 1, a0B, b0B, a0A, b0A, 1, 1, GATE4x, 1);
  }
  // ---- tail: tile 62 (stage B1(63), drain at P3), tile 63 (compute) ----
  TILEX(NTK - 2, 0, a0A, b0A, a0B, b0B, 1, 0, GATE0x, 1);
  TILEX(NTK - 1, 1, a0B, b0B, a0A, b0A, 0, 0, GNONE, 0);

  // ---- epilogue: C/D layout col = lane&15, row = (lane>>4)*4 + reg ----
  #pragma unroll
  for (int ni = 0; ni < 4; ++ni) {
    int col = tcol0 + wc * 64 + ni * 16 + lr;
    float bi = bias[col];
    #pragma unroll
    for (int mi = 0; mi < 8; ++mi) {
      int rr0 = trow0 + wr * 128 + mi * 16 + lg * 4;
      #pragma unroll
      for (int qq = 0; qq < 4; ++qq)
        C[(size_t)(rr0 + qq) * NN + col] = acc[mi][ni][qq] + bi;
    }
  }
}

// ---------------------------------------------------------------------------
// Kernel 5b (fallback, ws too small for xb): m97-style 128x128 GEMM with
// inline f32->bf16 A-staging.
// ---------------------------------------------------------------------------
constexpr int BM = 128, BN = 128, BK = 64;

__global__ __launch_bounds__(256) void gemm_fb(
    const float* __restrict__ xf,
    const unsigned short* __restrict__ wb, const float* __restrict__ bias,
    float* __restrict__ C)
{
  __shared__ __align__(16) unsigned short As2[BM * BK];
  __shared__ __align__(16) unsigned short Bs2[BN * BK];

  int bid = blockIdx.x;
  int swz = (bid & 7) * 256 + (bid >> 3);
  int tn = swz & 31;
  int tm = swz >> 5;

  int tid  = threadIdx.x;
  int lane = tid & 63;
  int wid  = tid >> 6;
  int wr = wid >> 1, wc = wid & 1;
  int lr = lane & 15;
  int lg = lane >> 4;

  f32x4 acc[4][4];
  #pragma unroll
  for (int i = 0; i < 4; i++)
    #pragma unroll
    for (int j = 0; j < 4; j++) {
      f32x4 z = {0.f, 0.f, 0.f, 0.f};
      acc[i][j] = z;
    }

  int srow = tid >> 3;
  int scol = (tid & 7) * 8;
  const size_t a_base = (size_t)(tm * BM) * MM;
  const size_t b_base = (size_t)(tn * BN) * MM;

  for (int k0 = 0; k0 < MM; k0 += BK) {
    #pragma unroll
    for (int c = 0; c < 4; c++) {
      int row = c * 32 + srow;
      gl_lds16(wb + b_base + (size_t)row * MM + k0 + scol,
               (char*)Bs2 + (c * 256 + wid * 64) * 16);
    }
    #pragma unroll
    for (int c = 0; c < 4; c++) {
      int row = c * 32 + srow;
      const float* s = xf + a_base + (size_t)row * MM + k0 + scol;
      f32x4 v0 = *(const f32x4*)s;
      f32x4 v1 = *(const f32x4*)(s + 4);
      ushort8 p;
      p[0] = f2bf(v0.x); p[1] = f2bf(v0.y); p[2] = f2bf(v0.z); p[3] = f2bf(v0.w);
      p[4] = f2bf(v1.x); p[5] = f2bf(v1.y); p[6] = f2bf(v1.z); p[7] = f2bf(v1.w);
      *(ushort8*)&As2[(c * 256 + tid) * 8] = p;
    }
    __syncthreads();

    #pragma unroll
    for (int kk = 0; kk < 2; kk++) {
      bf16x8 a[4], b[4];
      #pragma unroll
      for (int i = 0; i < 4; i++) {
        a[i] = *(const bf16x8*)&As2[(wr * 64 + i * 16 + lr) * BK + kk * 32 + lg * 8];
        b[i] = *(const bf16x8*)&Bs2[(wc * 64 + i * 16 + lr) * BK + kk * 32 + lg * 8];
      }
      #pragma unroll
      for (int i = 0; i < 4; i++)
        #pragma unroll
        for (int j = 0; j < 4; j++)
          acc[i][j] = __builtin_amdgcn_mfma_f32_16x16x32_bf16(a[i], b[j], acc[i][j], 0, 0, 0);
    }
    __syncthreads();
  }

  int gn0 = tn * BN + wc * 64;
  int gt0 = tm * BM + wr * 64;
  #pragma unroll
  for (int j = 0; j < 4; j++) {
    int gn = gn0 + j * 16 + lr;
    float bi = bias[gn];
    #pragma unroll
    for (int i = 0; i < 4; i++) {
      int t0 = gt0 + i * 16 + lg * 4;
      #pragma unroll
      for (int q = 0; q < 4; q++)
        C[(size_t)(t0 + q) * NN + gn] = acc[i][j][q] + bi;
    }
  }
}

// ---------------------------------------------------------------------------
extern "C" void kernel_launch(void* const* d_in, const int* in_sizes, int n_in,
                              void* d_out, int out_size, void* d_ws, size_t ws_size,
                              hipStream_t stream)
{
  const float* x    = (const float*)d_in[0];
  const float* W    = (const float*)d_in[1];
  const float* bias = (const float*)d_in[2];
  const float* thL  = (const float*)d_in[3];
  const float* thR  = (const float*)d_in[4];
  const float* elm  = (const float*)d_in[5];
  const float* brn  = (const float*)d_in[6];
  const int*   prL  = (const int*)d_in[7];
  const int*   prR  = (const int*)d_in[8];
  float* out = (float*)d_out;

  char* ws = (char*)d_ws;
  unsigned short* Wb = (unsigned short*)ws;          // N*M bf16 = 33.5 MB
  size_t off = (size_t)NN * MM * 2;
  float* colC = (float*)(ws + off); off += MM * 4;
  float* colS = (float*)(ws + off); off += MM * 4;
  int*   colP = (int*)  (ws + off); off += MM * 4;
  unsigned short* xb = (unsigned short*)(ws + off);  // T*M bf16 = 67 MB
  bool use_xb = ws_size >= off + (size_t)T_N * MM * 2;

  init_cols <<<16, 256, 0, stream>>>(colC, colS, colP);
  build_cols<<< 8, 256, 0, stream>>>(thR, prR, colC, colS, colP);

  if (use_xb) {
    weff_conv<<<S_L + 2048, 256, 0, stream>>>(W, brn, elm, thL, prL,
                                              colC, colS, colP, Wb, x, xb);
    gemm8<<<512, 512, 0, stream>>>(xb, Wb, bias, out);
  } else {
    weff_conv<<<S_L, 256, 0, stream>>>(W, brn, elm, thL, prL,
                                       colC, colS, colP, Wb, x, xb);
    gemm_fb<<<2048, 256, 0, stream>>>(x, Wb, bias, out);
  }
}